// Round 3
// baseline (632.087 us; speedup 1.0000x reference)
//
#include <hip/hip_runtime.h>

#define NEGV (-10000.0f)

constexpr int B_ = 512;
constexpr int S_ = 1024;
constexpr int NL_ = 49;
constexpr int L_ = 51;   // NL + 2; start = 49, end = 50

__device__ __forceinline__ float readlane_f(float v, int l) {
    return __int_as_float(__builtin_amdgcn_readlane(__float_as_int(v), l));
}

// v = max(v, dpp_move(v, CTRL)); CTRL must be a compile-time constant.
template <int CTRL>
__device__ __forceinline__ float dpp_max_step(float v) {
    int sh = __builtin_amdgcn_update_dpp(__float_as_int(v), __float_as_int(v),
                                         CTRL, 0xf, 0xf, false);
    return fmaxf(v, __int_as_float(sh));
}

// Full 64-lane max -> wave-uniform scalar (SGPR). Pure VALU (DPP), no LDS pipe.
__device__ __forceinline__ float wave_max_sgpr(float v) {
    v = dpp_max_step<0x111>(v);  // row_shr:1
    v = dpp_max_step<0x112>(v);  // row_shr:2
    v = dpp_max_step<0x114>(v);  // row_shr:4
    v = dpp_max_step<0x118>(v);  // row_shr:8
    v = dpp_max_step<0x142>(v);  // row_bcast:15
    v = dpp_max_step<0x143>(v);  // row_bcast:31
    return readlane_f(v, 63);
}

__global__ __launch_bounds__(64, 1) void crf_fwd(
    const float* __restrict__ logits,      // (B, S, NL)
    const float* __restrict__ transition,  // (L, L)
    const int*   __restrict__ labels,      // (B, S)
    const int*   __restrict__ lens,        // (B,)
    float*       __restrict__ out)         // (B,)
{
    const int b    = blockIdx.x;
    const int lane = threadIdx.x;
    const int len  = __builtin_amdgcn_readfirstlane(lens[b]);  // wave-uniform, >= 1

    const float* __restrict__ lg  = logits + (size_t)b * (S_ * NL_);
    const int*   __restrict__ lab = labels + (size_t)b * S_;

    // p broadcast buffers (double-buffered by step parity). 52 floats = 13 float4.
    __shared__ __align__(16) float pbuf[2][52];

    // ---- per-lane transition row (rows 0..48; start row dead after t=0,
    //      end column identically 0 in exp-space), exponentiated ----
    float Erow[NL_];
    float Tend, estart;
    {
        const bool st = (lane < NL_);
        const float* trow = transition + ((lane < L_) ? lane : 0) * L_;
        #pragma unroll
        for (int j = 0; j < NL_; ++j) {
            float tv = trow[j];
            Erow[j] = st ? __expf(tv) : 0.0f;
        }
        estart = __expf(trow[NL_]);                    // exp(T[lane][start])
        Tend   = (lane < L_) ? transition[(L_ - 1) * L_ + lane] : NEGV;
    }

    // ---- gold score: lane-parallel over time ----
    float g = 0.0f;
    for (int t = lane; t < S_; t += 64) {
        if (t < len) {
            int c = lab[t];
            int p = (t == 0) ? (L_ - 2) : lab[t - 1];
            g += lg[t * NL_ + c] + transition[c * L_ + p];
            if (t == len - 1) g += transition[(L_ - 1) * L_ + c];  // end transition
        }
    }
    #pragma unroll
    for (int o = 32; o >= 1; o >>= 1) g += __shfl_xor(g, o, 64);

    // ---- forward scan ----
    // t = 0 analytically: alpha_i = lg[0][i] + log(exp(T[i][start]))
    float alpha;
    {
        float lg0 = (lane < NL_) ? lg[lane] : NEGV;
        alpha = (lane < NL_) ? (lg0 + __logf(estart)) : NEGV;
    }
    float M = 0.0f;   // max of alpha BEFORE step 0 (start vector) = 0; stale-by-1

    auto loadlg = [&](int t) -> float {
        float v = NEGV;
        if (lane < NL_) v = lg[t * NL_ + lane];
        return v;
    };

    float b0 = loadlg(1), b1 = loadlg(2), b2 = loadlg(3), b3 = loadlg(4);
    float b4 = loadlg(5), b5 = loadlg(6), b6 = loadlg(7), b7 = loadlg(8);

    auto substep = [&](float cur, int t, int par) {
        float p = __expf(alpha - M);            // bounded: alpha - stale_max small
        if (lane < NL_) pbuf[par][lane] = p;    // 1 ds_write_b32
        float Mn = wave_max_sgpr(alpha);        // DPP chain overlaps LDS round-trip
        // broadcast-read p: 13 x ds_read_b128 at wave-uniform addresses
        const float4* pv = (const float4*)pbuf[par];
        float4 q[13];
        #pragma unroll
        for (int k = 0; k < 13; ++k) q[k] = pv[k];
        // y_i = sum_{j<49} E[i][j] * p_j  — same accumulator/order as before:
        // y0: j=0,4,...,48; y1: 1,5,...; y2: 2,6,...; y3: 3,7,...
        float y0 = 0.f, y1 = 0.f, y2 = 0.f, y3 = 0.f;
        #pragma unroll
        for (int k = 0; k < 12; ++k) {
            y0 = fmaf(q[k].x, Erow[4 * k + 0], y0);
            y1 = fmaf(q[k].y, Erow[4 * k + 1], y1);
            y2 = fmaf(q[k].z, Erow[4 * k + 2], y2);
            y3 = fmaf(q[k].w, Erow[4 * k + 3], y3);
        }
        y0 = fmaf(q[12].x, Erow[48], y0);
        float y = (y0 + y1) + (y2 + y3);
        float anew = cur + M + __logf(y);
        if (t < len && lane < NL_) alpha = anew;   // uniform t<len; cndmask on lane
        M = Mn;
    };

    const int tEnd = 1 + (((len - 1) + 7) & ~7);   // steps t = 1 .. len-1, padded to 8
    for (int t = 1; t < tEnd; t += 8) {
        int t8  = t + 8;  t8  = (t8  < S_) ? t8  : (S_ - 1);
        int t9  = t + 9;  t9  = (t9  < S_) ? t9  : (S_ - 1);
        int t10 = t + 10; t10 = (t10 < S_) ? t10 : (S_ - 1);
        int t11 = t + 11; t11 = (t11 < S_) ? t11 : (S_ - 1);
        int t12 = t + 12; t12 = (t12 < S_) ? t12 : (S_ - 1);
        int t13 = t + 13; t13 = (t13 < S_) ? t13 : (S_ - 1);
        int t14 = t + 14; t14 = (t14 < S_) ? t14 : (S_ - 1);
        int t15 = t + 15; t15 = (t15 < S_) ? t15 : (S_ - 1);
        substep(b0, t + 0, 0); b0 = loadlg(t8);
        substep(b1, t + 1, 1); b1 = loadlg(t9);
        substep(b2, t + 2, 0); b2 = loadlg(t10);
        substep(b3, t + 3, 1); b3 = loadlg(t11);
        substep(b4, t + 4, 0); b4 = loadlg(t12);
        substep(b5, t + 5, 1); b5 = loadlg(t13);
        substep(b6, t + 6, 0); b6 = loadlg(t14);
        substep(b7, t + 7, 1); b7 = loadlg(t15);
    }

    // ---- norm = LSE_i(alpha_i + T[end, i]) ----
    float x = (lane < L_) ? (alpha + Tend) : NEGV;
    float mx = x;
    #pragma unroll
    for (int o = 32; o >= 1; o >>= 1) mx = fmaxf(mx, __shfl_xor(mx, o, 64));
    float e = __expf(x - mx);
    #pragma unroll
    for (int o = 32; o >= 1; o >>= 1) e += __shfl_xor(e, o, 64);
    float norm = mx + __logf(e);

    if (lane == 0) out[b] = g - norm;
}

extern "C" void kernel_launch(void* const* d_in, const int* in_sizes, int n_in,
                              void* d_out, int out_size, void* d_ws, size_t ws_size,
                              hipStream_t stream) {
    const float* logits     = (const float*)d_in[0];
    const float* transition = (const float*)d_in[1];
    const int*   labels     = (const int*)d_in[2];
    const int*   lens       = (const int*)d_in[3];
    float*       out        = (float*)d_out;
    crf_fwd<<<dim3(B_), dim3(64), 0, stream>>>(logits, transition, labels, lens, out);
}

// Round 4
// 524.818 us; speedup vs baseline: 1.2044x; 1.2044x over previous
//
#include <hip/hip_runtime.h>

#define NEGV (-10000.0f)

constexpr int B_ = 512;
constexpr int S_ = 1024;
constexpr int NL_ = 49;
constexpr int L_ = 51;   // NL + 2; start = 49, end = 50

__device__ __forceinline__ float readlane_f(float v, int l) {
    return __int_as_float(__builtin_amdgcn_readlane(__float_as_int(v), l));
}

// v = max(v, dpp_move(v, CTRL)); CTRL must be a compile-time constant.
template <int CTRL>
__device__ __forceinline__ float dpp_max_step(float v) {
    int sh = __builtin_amdgcn_update_dpp(__float_as_int(v), __float_as_int(v),
                                         CTRL, 0xf, 0xf, false);
    return fmaxf(v, __int_as_float(sh));
}

// Full 64-lane max -> wave-uniform scalar (SGPR). Pure VALU (DPP), no LDS pipe.
__device__ __forceinline__ float wave_max_sgpr(float v) {
    v = dpp_max_step<0x111>(v);  // row_shr:1
    v = dpp_max_step<0x112>(v);  // row_shr:2
    v = dpp_max_step<0x114>(v);  // row_shr:4
    v = dpp_max_step<0x118>(v);  // row_shr:8
    v = dpp_max_step<0x142>(v);  // row_bcast:15
    v = dpp_max_step<0x143>(v);  // row_bcast:31
    return readlane_f(v, 63);
}

__global__ __launch_bounds__(64, 1) void crf_fwd(
    const float* __restrict__ logits,      // (B, S, NL)
    const float* __restrict__ transition,  // (L, L)
    const int*   __restrict__ labels,      // (B, S)
    const int*   __restrict__ lens,        // (B,)
    float*       __restrict__ out)         // (B,)
{
    const int b    = blockIdx.x;
    const int lane = threadIdx.x;
    const int len  = __builtin_amdgcn_readfirstlane(lens[b]);  // wave-uniform, >= 1

    const float* __restrict__ lg  = logits + (size_t)b * (S_ * NL_);
    const int*   __restrict__ lab = labels + (size_t)b * S_;

    // ---- per-lane transition row (rows 0..48; start row dead after t=0,
    //      end column identically 0 in exp-space), exponentiated ----
    float Erow[NL_];
    float Tend, estart;
    {
        const bool st = (lane < NL_);
        const float* trow = transition + ((lane < L_) ? lane : 0) * L_;
        #pragma unroll
        for (int j = 0; j < NL_; ++j) {
            float tv = trow[j];
            Erow[j] = st ? __expf(tv) : 0.0f;
        }
        estart = __expf(trow[NL_]);                    // exp(T[lane][start])
        Tend   = (lane < L_) ? transition[(L_ - 1) * L_ + lane] : NEGV;
    }

    // ---- gold score: lane-parallel over time ----
    float g = 0.0f;
    for (int t = lane; t < S_; t += 64) {
        if (t < len) {
            int c = lab[t];
            int p = (t == 0) ? (L_ - 2) : lab[t - 1];
            g += lg[t * NL_ + c] + transition[c * L_ + p];
            if (t == len - 1) g += transition[(L_ - 1) * L_ + c];  // end transition
        }
    }
    #pragma unroll
    for (int o = 32; o >= 1; o >>= 1) g += __shfl_xor(g, o, 64);

    // ---- forward scan ----
    // t = 0 analytically: alpha_i = lg[0][i] + log(exp(T[i][start]))
    float alpha;
    {
        float lg0 = (lane < NL_) ? lg[lane] : NEGV;
        alpha = (lane < NL_) ? (lg0 + __logf(estart)) : NEGV;
    }
    float M = 0.0f;   // max of alpha BEFORE step 0 (start vector) = 0; stale-by-1

    auto loadlg = [&](int t) -> float {
        float v = NEGV;
        if (lane < NL_) v = lg[t * NL_ + lane];
        return v;
    };

    float b0 = loadlg(1), b1 = loadlg(2), b2 = loadlg(3), b3 = loadlg(4);
    float b4 = loadlg(5), b5 = loadlg(6), b6 = loadlg(7), b7 = loadlg(8);

    auto substep = [&](float cur, int t) {
        float p = __expf(alpha - M);        // bounded: alpha - stale_max small
        // Hoist ALL broadcasts first: v_readlane writes SGPR; consuming fma must
        // not follow immediately (VALU->SGPR->VALU wait-states). Age each SGPR
        // by the full broadcast block before any fma reads it.
        float ps[NL_];
        #pragma unroll
        for (int j = 0; j < NL_; ++j) ps[j] = readlane_f(p, j);
        __builtin_amdgcn_sched_barrier(0);  // keep fmas from being hoisted between
        // y_i = sum_{j<49} E[i][j] * p_j  — same accumulators/order as before:
        float y0 = 0.f, y1 = 0.f, y2 = 0.f, y3 = 0.f;
        #pragma unroll
        for (int j = 0; j < 48; j += 4) {
            y0 = fmaf(ps[j + 0], Erow[j + 0], y0);
            y1 = fmaf(ps[j + 1], Erow[j + 1], y1);
            y2 = fmaf(ps[j + 2], Erow[j + 2], y2);
            y3 = fmaf(ps[j + 3], Erow[j + 3], y3);
        }
        y0 = fmaf(ps[48], Erow[48], y0);
        float Mn = wave_max_sgpr(alpha);    // for NEXT step; overlaps fma tail
        float y = (y0 + y1) + (y2 + y3);
        float anew = cur + M + __logf(y);
        if (t < len && lane < NL_) alpha = anew;   // uniform t<len; cndmask on lane
        M = Mn;
    };

    const int tEnd = 1 + (((len - 1) + 7) & ~7);   // steps t = 1 .. len-1, padded to 8
    for (int t = 1; t < tEnd; t += 8) {
        int t8  = t + 8;  t8  = (t8  < S_) ? t8  : (S_ - 1);
        int t9  = t + 9;  t9  = (t9  < S_) ? t9  : (S_ - 1);
        int t10 = t + 10; t10 = (t10 < S_) ? t10 : (S_ - 1);
        int t11 = t + 11; t11 = (t11 < S_) ? t11 : (S_ - 1);
        int t12 = t + 12; t12 = (t12 < S_) ? t12 : (S_ - 1);
        int t13 = t + 13; t13 = (t13 < S_) ? t13 : (S_ - 1);
        int t14 = t + 14; t14 = (t14 < S_) ? t14 : (S_ - 1);
        int t15 = t + 15; t15 = (t15 < S_) ? t15 : (S_ - 1);
        substep(b0, t + 0); b0 = loadlg(t8);
        substep(b1, t + 1); b1 = loadlg(t9);
        substep(b2, t + 2); b2 = loadlg(t10);
        substep(b3, t + 3); b3 = loadlg(t11);
        substep(b4, t + 4); b4 = loadlg(t12);
        substep(b5, t + 5); b5 = loadlg(t13);
        substep(b6, t + 6); b6 = loadlg(t14);
        substep(b7, t + 7); b7 = loadlg(t15);
    }

    // ---- norm = LSE_i(alpha_i + T[end, i]) ----
    float x = (lane < L_) ? (alpha + Tend) : NEGV;
    float mx = x;
    #pragma unroll
    for (int o = 32; o >= 1; o >>= 1) mx = fmaxf(mx, __shfl_xor(mx, o, 64));
    float e = __expf(x - mx);
    #pragma unroll
    for (int o = 32; o >= 1; o >>= 1) e += __shfl_xor(e, o, 64);
    float norm = mx + __logf(e);

    if (lane == 0) out[b] = g - norm;
}

extern "C" void kernel_launch(void* const* d_in, const int* in_sizes, int n_in,
                              void* d_out, int out_size, void* d_ws, size_t ws_size,
                              hipStream_t stream) {
    const float* logits     = (const float*)d_in[0];
    const float* transition = (const float*)d_in[1];
    const int*   labels     = (const int*)d_in[2];
    const int*   lens       = (const int*)d_in[3];
    float*       out        = (float*)d_out;
    crf_fwd<<<dim3(B_), dim3(64), 0, stream>>>(logits, transition, labels, lens, out);
}